// Round 6
// baseline (697.052 us; speedup 1.0000x reference)
//
#include <hip/hip_runtime.h>
#include <hip/hip_bf16.h>
#include <stdint.h>

// MegaNeRF fused MoE-MLP for MI355X (gfx950).  Round 6.
// E=8 experts, MLP 90->256->256->256->4, N=131072 points, inverse-distance gating.
//
// Round-6: (a) h kept in LDS in MFMA *A-fragment layout* [mt][kq][lane][8]
// -> ds_read_b128 at frag*1024+lane*16, ZERO read bank conflicts (the r1-r5
// row-major layout was ~8-way on every A-read; 1.94e7 conflict cycles).
// (b) 1024-thread blocks, 16 waves, wave tile 32x64 -> acc[2][4]=32 regs;
// total ~100 regs forced <=128 by block size -> no spill, 4 waves/SIMD.

#define NE    8
#define FIN   90
#define HD    256
#define NOUT  4
#define XC    93          // 3 + FIN columns in x

#define MT        128     // points per block
#define NTHREADS  1024    // 16 waves: 4 (wr) x 4 (wc)

#define KQ1   3           // ceil(90/32) -> K padded to 96
#define KQH   8           // 256/32
#define NBH   16          // 256/16

#define W1_ELEMS (NE*NBH*KQ1*512)   // 196608
#define W2_ELEMS (NE*NBH*KQH*512)   // 524288
#define WO_ELEMS (NE*KQH*512)       // 32768  (OUT padded 4->16)
#define WTOT     (W1_ELEMS + 2*W2_ELEMS + WO_ELEMS)   // 1277952 elems

typedef __attribute__((ext_vector_type(8))) short bf16x8;
typedef __attribute__((ext_vector_type(4))) float f32x4;

__device__ __forceinline__ unsigned short f2bf(float f) {   // cold path only
  union { float f; uint32_t u; } v; v.f = f;
  v.u += 0x7fffu + ((v.u >> 16) & 1u);   // RNE
  return (unsigned short)(v.u >> 16);
}

// ---------------------------------------------------------------------------
// Weight conversion: f32 [e][k][n] -> bf16 B-fragments [frag][lane][8],
// frag = (e*NBH + nb)*KQ + kq, elem (lane,j) = W[kq*32+(lane>>4)*8+j][nb*16+(lane&15)].
// ---------------------------------------------------------------------------
__global__ __launch_bounds__(256)
void convert_weights(const float* __restrict__ W1, const float* __restrict__ W2,
                     const float* __restrict__ W3, const float* __restrict__ Wo,
                     unsigned short* __restrict__ ws) {
  int idx = blockIdx.x * 256 + threadIdx.x;
  int j = idx & 7;
  int lane = (idx >> 3) & 63;
  int n16 = lane & 15;
  int kof = ((lane >> 4) << 3) + j;
  if (idx < W1_ELEMS) {
    int f = idx >> 9;
    int kq = f % KQ1; f /= KQ1;
    int nb = f % NBH; int e = f / NBH;
    int n = nb*16 + n16, k = kq*32 + kof;
    float v = (k < FIN) ? W1[(e*FIN + k)*HD + n] : 0.f;
    ws[idx] = f2bf(v);
  } else if (idx < W1_ELEMS + 2*W2_ELEMS) {
    int t = idx - W1_ELEMS;
    const float* W = (t < W2_ELEMS) ? W2 : W3;
    int u = (t < W2_ELEMS) ? t : (t - W2_ELEMS);
    int f = u >> 9;
    int kq = f % KQH; f /= KQH;
    int nb = f % NBH; int e = f / NBH;
    int n = nb*16 + n16, k = kq*32 + kof;
    ws[idx] = f2bf(W[(e*HD + k)*HD + n]);
  } else if (idx < WTOT) {
    int t = idx - (W1_ELEMS + 2*W2_ELEMS);
    int f = t >> 9;
    int kq = f % KQH; int e = f / KQH;
    int k = kq*32 + kof;
    float v = (n16 < NOUT) ? Wo[(e*HD + k)*NOUT + n16] : 0.f;
    ws[idx] = f2bf(v);
  }
}

// ---------------------------------------------------------------------------
// X conversion: f32 x[:,3:] -> bf16 A-fragments, frag f = r16*KQ1 + kq,
// elem (lane,j) = X[r16*16+(lane&15)][kq*32+(lane>>4)*8+j]  (0 beyond FIN).
// ---------------------------------------------------------------------------
__global__ __launch_bounds__(256)
void convert_x(const float* __restrict__ x, unsigned short* __restrict__ xs, int nfrag) {
  int idx = blockIdx.x * 256 + threadIdx.x;
  if (idx >= nfrag * 512) return;
  int j = idx & 7;
  int lane = (idx >> 3) & 63;
  int f = idx >> 9;
  int kq = f % KQ1;
  int r16 = f / KQ1;
  int row = r16*16 + (lane & 15);
  int k = kq*32 + ((lane >> 4) << 3) + j;
  float v = (k < FIN) ? x[(size_t)row*XC + 3 + k] : 0.f;
  xs[idx] = f2bf(v);
}

// ---------------------------------------------------------------------------
// Epilogue: relu + f32->bf16, scatter C frags into the A-frag-layout h buffer.
// C/D layout: ch(col)=lane&15, row=(lane>>4)*4+reg.   h element (row,ch) lives
// at elem ((row/16)*8 + ch/32)*512 + ((row%16) + 16*((ch%32)/8))*8 + (ch%8).
// Per-thread: base + mf*4096 + nf*256 + j*8  (all imm offsets).
// ---------------------------------------------------------------------------
__device__ __forceinline__ void store_frag(f32x4 (&acc)[2][4], unsigned short* hF,
                                           int wr, int wc, int l15, int l4) {
  unsigned short* base = hF + (wr*16 + wc*2)*512 + l4*32 + (l15 >> 3)*128 + (l15 & 7);
#pragma unroll
  for (int mf = 0; mf < 2; ++mf)
#pragma unroll
    for (int nf = 0; nf < 4; ++nf)
#pragma unroll
      for (int j = 0; j < 4; ++j)
        *reinterpret_cast<__hip_bfloat16*>(&base[mf*4096 + nf*256 + j*8]) =
            __float2bfloat16(fmaxf(acc[mf][nf][j], 0.f));
}

// One hidden layer IN PLACE on the frag-layout h: reads -> sync -> store -> sync.
__device__ __forceinline__ void layerH(unsigned short* hF,
                                       const unsigned short* __restrict__ fw,
                                       const float* __restrict__ bias,
                                       int wr, int wc, int l15, int l4, int lane) {
  f32x4 acc[2][4];
#pragma unroll
  for (int nf = 0; nf < 4; ++nf) {
    float bv = bias[wc*64 + nf*16 + l15];      // bias folded into acc init
#pragma unroll
    for (int mf = 0; mf < 2; ++mf)
      acc[mf][nf] = f32x4{bv, bv, bv, bv};
  }

  const unsigned short* aBase = hF + lane*8;   // one addr reg; frag offsets are imm
#pragma unroll
  for (int kq = 0; kq < KQH; ++kq) {
    bf16x8 a[2];
#pragma unroll
    for (int mf = 0; mf < 2; ++mf)
      a[mf] = *(const bf16x8*)(aBase + ((wr*2 + mf)*KQH + kq)*512);
    const unsigned short* bp = fw + ((((wc*4)*KQH) + kq) << 9) + lane*8;
#pragma unroll
    for (int nf = 0; nf < 4; ++nf) {
      bf16x8 b = *(const bf16x8*)(bp + ((nf*KQH) << 9));
#pragma unroll
      for (int mf = 0; mf < 2; ++mf)
        acc[mf][nf] = __builtin_amdgcn_mfma_f32_16x16x32_bf16(a[mf], b, acc[mf][nf], 0, 0, 0);
    }
  }
  __syncthreads();                 // every wave finished reading hF
  store_frag(acc, hF, wr, wc, l15, l4);
  __syncthreads();                 // hF fully rewritten
}

template<bool XSTAGED>
__global__ __launch_bounds__(NTHREADS)
void meganerf_fused(const float* __restrict__ x, const float* __restrict__ cent,
                    const float* __restrict__ b1, const float* __restrict__ b2,
                    const float* __restrict__ b3, const float* __restrict__ bo,
                    const unsigned short* __restrict__ wf,
                    const unsigned short* __restrict__ xs,
                    float* __restrict__ out) {
  __shared__ unsigned short hF[8 * KQH * 512];  // 65536 B, A-frag layout
  __shared__ float wcl[MT * NE];                // 4096 B
  __shared__ float oacc[MT * NOUT];             // 2048 B   -> total 71680 B

  const int tid = threadIdx.x;
  const int lane = tid & 63;
  const int wv = tid >> 6;      // 0..15
  const int wr = wv >> 2;       // row group 0..3 (32 rows each)
  const int wc = wv & 3;        // col group 0..3 (64 cols each)
  const int l15 = lane & 15, l4 = lane >> 4;
  const int row0 = blockIdx.x * MT;

  // --- cluster weights (strict IEEE f32, no contraction: must bit-match np) ---
  if (tid < MT) {
    const int p = row0 + tid;
    float px = x[p*XC + 1], py = x[p*XC + 2];
    float d[NE]; float mind = 3.4e38f;
#pragma unroll
    for (int e = 0; e < NE; ++e) {
      float dx = px - cent[e*3 + 1];
      float dy = py - cent[e*3 + 2];
      d[e] = __fsqrt_rn(__fmul_rn(dx, dx) + __fmul_rn(dy, dy));
      mind = fminf(mind, d[e]);
    }
    float m = 1.5f * mind, s = 0.f, inv[NE];
#pragma unroll
    for (int e = 0; e < NE; ++e) {
      float iv = (d[e] > m) ? 0.f : 1.f / (d[e] + 1e-8f);
      inv[e] = iv; s += iv;
    }
#pragma unroll
    for (int e = 0; e < NE; ++e) wcl[tid*NE + e] = inv[e] / s;
  }
  if (tid < MT*NOUT) oacc[tid] = 0.f;

  // --- fallback only: X fragments in registers ---
  bf16x8 xf[XSTAGED ? 1 : 2][KQ1];
  if constexpr (!XSTAGED) {
    const int rbase = row0 + wr*32;
#pragma unroll
    for (int mf = 0; mf < 2; ++mf) {
      const float* src = x + (size_t)(rbase + mf*16 + l15)*XC + 3;
#pragma unroll
      for (int kq = 0; kq < KQ1; ++kq) {
        int kb = kq*32 + l4*8;
        bf16x8 v;
#pragma unroll
        for (int j = 0; j < 8; ++j) {
          float f = (kb + j < FIN) ? src[kb + j] : 0.f;
          v[j] = (short)f2bf(f);
        }
        xf[mf][kq] = v;
      }
    }
  }
  __syncthreads();

  const unsigned short* fw1 = wf;
  const unsigned short* fw2 = wf + W1_ELEMS;
  const unsigned short* fw3 = fw2 + W2_ELEMS;
  const unsigned short* fwo = fw3 + W2_ELEMS;
  // staged X: fragment base for this wave's two 16-row tiles
  const unsigned short* xsb = xs + ((size_t)(blockIdx.x*8 + wr*2)*KQ1)*512 + lane*8;

  for (int e = 0; e < NE; ++e) {
    // ---- layer 1: X(128x96) @ W1 -> relu -> hF ----
    {
      f32x4 acc[2][4];
#pragma unroll
      for (int nf = 0; nf < 4; ++nf) {
        float bv = b1[e*HD + wc*64 + nf*16 + l15];
#pragma unroll
        for (int mf = 0; mf < 2; ++mf)
          acc[mf][nf] = f32x4{bv, bv, bv, bv};
      }
#pragma unroll
      for (int kq = 0; kq < KQ1; ++kq) {
        bf16x8 a1[2];
#pragma unroll
        for (int mf = 0; mf < 2; ++mf) {
          if constexpr (XSTAGED)
            a1[mf] = *(const bf16x8*)(xsb + (mf*KQ1 + kq)*512);
          else
            a1[mf] = xf[mf][kq];
        }
        const unsigned short* bp = fw1 + (((e*NBH + wc*4)*KQ1 + kq) << 9) + lane*8;
#pragma unroll
        for (int nf = 0; nf < 4; ++nf) {
          bf16x8 b = *(const bf16x8*)(bp + ((nf*KQ1) << 9));
#pragma unroll
          for (int mf = 0; mf < 2; ++mf)
            acc[mf][nf] = __builtin_amdgcn_mfma_f32_16x16x32_bf16(a1[mf], b, acc[mf][nf], 0, 0, 0);
        }
      }
      store_frag(acc, hF, wr, wc, l15, l4);
    }
    __syncthreads();

    // ---- layer 2, layer 3: in-place frag-layout hF ----
    layerH(hF, fw2 + (e << 16), b2 + e*HD, wr, wc, l15, l4, lane);
    layerH(hF, fw3 + (e << 16), b3 + e*HD, wr, wc, l15, l4, lane);

    // ---- layer 4 (OUT=4, padded to 16) + gated accumulation; waves 0..7 ----
    if (wv < 8) {
      f32x4 acc = {0.f, 0.f, 0.f, 0.f};
#pragma unroll
      for (int kq = 0; kq < KQH; ++kq) {
        bf16x8 a = *(const bf16x8*)(hF + (wv*KQH + kq)*512 + lane*8);
        bf16x8 b = *(const bf16x8*)(fwo + ((e*KQH + kq) << 9) + lane*8);
        acc = __builtin_amdgcn_mfma_f32_16x16x32_bf16(a, b, acc, 0, 0, 0);
      }
      if (l15 < NOUT) {
        float bv = bo[e*NOUT + l15];
#pragma unroll
        for (int j = 0; j < 4; ++j) {
          int row = wv*16 + l4*4 + j;            // each thread owns its slots -> no race
          oacc[row*NOUT + l15] += wcl[row*NE + e] * (acc[j] + bv);
        }
      }
    }
    __syncthreads();   // L4 reads of hF done; next expert's L1 may rewrite hF
  }

  if (tid < MT*NOUT)
    out[(size_t)row0*NOUT + tid] = oacc[tid];    // 512 contiguous f32, coalesced
}

extern "C" void kernel_launch(void* const* d_in, const int* in_sizes, int n_in,
                              void* d_out, int out_size, void* d_ws, size_t ws_size,
                              hipStream_t stream) {
  const float* x    = (const float*)d_in[0];
  const float* cent = (const float*)d_in[1];
  const float* W1   = (const float*)d_in[2];
  const float* b1   = (const float*)d_in[3];
  const float* W2   = (const float*)d_in[4];
  const float* b2   = (const float*)d_in[5];
  const float* W3   = (const float*)d_in[6];
  const float* b3   = (const float*)d_in[7];
  const float* Wo   = (const float*)d_in[8];
  const float* bo   = (const float*)d_in[9];
  float* out = (float*)d_out;
  unsigned short* wsb = (unsigned short*)d_ws;

  const int N = in_sizes[0] / XC;                 // 131072
  const int nfragX = (N/16) * KQ1;                // 24576 fragments
  const size_t wbytes = (size_t)WTOT * 2;         // 2,555,904
  const size_t xbytes = (size_t)nfragX * 512 * 2; // 25,165,824

  convert_weights<<<dim3((WTOT + 255) / 256), dim3(256), 0, stream>>>(W1, W2, W3, Wo, wsb);

  if (ws_size >= wbytes + xbytes) {
    unsigned short* xsb2 = wsb + WTOT;
    convert_x<<<dim3((nfragX*512 + 255) / 256), dim3(256), 0, stream>>>(x, xsb2, nfragX);
    meganerf_fused<true><<<dim3(N / MT), dim3(NTHREADS), 0, stream>>>(
        x, cent, b1, b2, b3, bo, wsb, xsb2, out);
  } else {
    meganerf_fused<false><<<dim3(N / MT), dim3(NTHREADS), 0, stream>>>(
        x, cent, b1, b2, b3, bo, wsb, wsb, out);
  }
}

// Round 8
// 448.412 us; speedup vs baseline: 1.5545x; 1.5545x over previous
//
#include <hip/hip_runtime.h>
#include <hip/hip_bf16.h>
#include <stdint.h>

// MegaNeRF fused MoE-MLP for MI355X (gfx950).  Round 8.
// E=8 experts, MLP 90->256->256->256->4, N=131072 points, inverse-distance gating.
//
// Round-8: swapped-operand layers: h'^T = W^T h^T via mfma(A=W-frag, B=h-frag).
// D (lane=point, regs=4 consecutive channels) packs into ONE b64 LDS store in
// next layer's B-frag layout; reads are lane-linear ds_read_b128.  Both LDS
// sides conflict-free with only standard instructions (no tr-read, no asm).
// Final layer's 4 outputs land in one thread -> gated accumulation in regs.
// Fragments identical to r1-r6 (verified).  ~124 total regs -> (512,4), no spill.

#define NE    8
#define FIN   90
#define HD    256
#define NOUT  4
#define XC    93          // 3 + FIN columns in x

#define MT        128     // points per block
#define NTHREADS  512     // 8 waves: 4 (wch) x 2 (wpt)

#define KQ1   3           // ceil(90/32) -> K padded to 96
#define KQH   8           // 256/32
#define NBH   16          // 256/16

#define W1_ELEMS (NE*NBH*KQ1*512)   // 196608
#define W2_ELEMS (NE*NBH*KQH*512)   // 524288
#define WO_ELEMS (NE*KQH*512)       // 32768  (OUT padded 4->16)
#define WTOT     (W1_ELEMS + 2*W2_ELEMS + WO_ELEMS)   // 1277952 elems

typedef __attribute__((ext_vector_type(8))) short bf16x8;
typedef __attribute__((ext_vector_type(4))) short bf16x4;
typedef __attribute__((ext_vector_type(4))) float f32x4;

__device__ __forceinline__ unsigned short f2bf(float f) {   // cold path only
  union { float f; uint32_t u; } v; v.f = f;
  v.u += 0x7fffu + ((v.u >> 16) & 1u);   // RNE
  return (unsigned short)(v.u >> 16);
}

__device__ __forceinline__ short relu_bf(float f) {         // hot epilogue
  __hip_bfloat16 t = __float2bfloat16(fmaxf(f, 0.f));       // compiler fuses cvt_pk
  return __builtin_bit_cast(short, t);
}

// ---------------------------------------------------------------------------
// Weight conversion (IDENTICAL to r1-r6, 6x verified): f32 [e][k][n] -> bf16
// fragments [frag][lane][8], frag = (e*NBH + nb)*KQ + kq,
// elem (lane,j) = W[k = kq*32+(lane>>4)*8+j][n = nb*16+(lane&15)].
// ---------------------------------------------------------------------------
__global__ __launch_bounds__(256)
void convert_weights(const float* __restrict__ W1, const float* __restrict__ W2,
                     const float* __restrict__ W3, const float* __restrict__ Wo,
                     unsigned short* __restrict__ ws) {
  int idx = blockIdx.x * 256 + threadIdx.x;
  int j = idx & 7;
  int lane = (idx >> 3) & 63;
  int n16 = lane & 15;
  int kof = ((lane >> 4) << 3) + j;
  if (idx < W1_ELEMS) {
    int f = idx >> 9;
    int kq = f % KQ1; f /= KQ1;
    int nb = f % NBH; int e = f / NBH;
    int n = nb*16 + n16, k = kq*32 + kof;
    float v = (k < FIN) ? W1[(e*FIN + k)*HD + n] : 0.f;
    ws[idx] = f2bf(v);
  } else if (idx < W1_ELEMS + 2*W2_ELEMS) {
    int t = idx - W1_ELEMS;
    const float* W = (t < W2_ELEMS) ? W2 : W3;
    int u = (t < W2_ELEMS) ? t : (t - W2_ELEMS);
    int f = u >> 9;
    int kq = f % KQH; f /= KQH;
    int nb = f % NBH; int e = f / NBH;
    int n = nb*16 + n16, k = kq*32 + kof;
    ws[idx] = f2bf(W[(e*HD + k)*HD + n]);
  } else if (idx < WTOT) {
    int t = idx - (W1_ELEMS + 2*W2_ELEMS);
    int f = t >> 9;
    int kq = f % KQH; int e = f / KQH;
    int k = kq*32 + kof;
    float v = (n16 < NOUT) ? Wo[(e*HD + k)*NOUT + n16] : 0.f;
    ws[idx] = f2bf(v);
  }
}

// ---------------------------------------------------------------------------
// X conversion (IDENTICAL to r5/r6): f32 x[:,3:] -> bf16 fragments, frag
// f = r16*KQ1 + kq, elem (lane,j) = X[r16*16+(lane&15)][kq*32+(lane>>4)*8+j].
// Consumed as the B-operand (lane&15 = point col).
// ---------------------------------------------------------------------------
__global__ __launch_bounds__(256)
void convert_x(const float* __restrict__ x, unsigned short* __restrict__ xs, int nfrag) {
  int idx = blockIdx.x * 256 + threadIdx.x;
  if (idx >= nfrag * 512) return;
  int j = idx & 7;
  int lane = (idx >> 3) & 63;
  int f = idx >> 9;
  int kq = f % KQ1;
  int r16 = f / KQ1;
  int row = r16*16 + (lane & 15);
  int k = kq*32 + ((lane >> 4) << 3) + j;
  float v = (k < FIN) ? x[(size_t)row*XC + 3 + k] : 0.f;
  xs[idx] = f2bf(v);
}

// ---------------------------------------------------------------------------
// Epilogue: relu + pack 4 consecutive channels (D regs j=0..3) -> one b64
// store into hB's B-frag layout [mtile][kq][lane'][j'].
// D: point m = wpt*64+pf*16+l15 (col), channel c = wch*64+cf*16+l4*4+j (row).
// Target: mtile=wpt*4+pf, kq=c>>5, lane'=(m&15)+16*((c&31)>>3), j'=c&7.
// Bank phases = 4 (64-lane b64 minimum) -> conflict-free.
// ---------------------------------------------------------------------------
__device__ __forceinline__ void store_hB(f32x4 (&acc)[4][4], unsigned short* hB,
                                         int wch, int wpt, int l15, int l4) {
  unsigned short* base = hB + wpt*16384 + wch*1024 + l15*8 + (l4>>1)*128 + (l4&1)*4;
#pragma unroll
  for (int cf = 0; cf < 4; ++cf)
#pragma unroll
    for (int pf = 0; pf < 4; ++pf) {
      bf16x4 s;
      s.x = relu_bf(acc[cf][pf][0]);
      s.y = relu_bf(acc[cf][pf][1]);
      s.z = relu_bf(acc[cf][pf][2]);
      s.w = relu_bf(acc[cf][pf][3]);
      *reinterpret_cast<bf16x4*>(base + pf*4096 + (cf>>1)*512 + (cf&1)*256) = s;
    }
}

// One hidden layer IN PLACE: h'^T = relu(W^T h^T + b).  A=W-frag (global),
// B=h-frag (LDS, lane-linear b128).  reads -> sync -> packed stores -> sync.
__device__ __forceinline__ void layerH(unsigned short* hB,
                                       const unsigned short* __restrict__ fw,
                                       const float* __restrict__ bias,
                                       int wch, int wpt, int l15, int l4, int lane) {
  f32x4 acc[4][4];   // [cf][pf]
#pragma unroll
  for (int cf = 0; cf < 4; ++cf) {
    f32x4 bv = *reinterpret_cast<const f32x4*>(&bias[wch*64 + cf*16 + l4*4]);
#pragma unroll
    for (int pf = 0; pf < 4; ++pf)
      acc[cf][pf] = bv;
  }

  const unsigned short* rb = hB + wpt*16384 + lane*8;
#pragma unroll
  for (int kq = 0; kq < KQH; ++kq) {
    bf16x8 aw[4];
#pragma unroll
    for (int cf = 0; cf < 4; ++cf)
      aw[cf] = *(const bf16x8*)(fw + ((((wch*4 + cf)*KQH) + kq) << 9) + lane*8);
#pragma unroll
    for (int pf = 0; pf < 4; ++pf) {
      bf16x8 bh = *(const bf16x8*)(rb + pf*4096 + kq*512);
#pragma unroll
      for (int cf = 0; cf < 4; ++cf)
        acc[cf][pf] = __builtin_amdgcn_mfma_f32_16x16x32_bf16(aw[cf], bh, acc[cf][pf], 0, 0, 0);
    }
  }
  __syncthreads();                 // every wave finished reading hB
  store_hB(acc, hB, wch, wpt, l15, l4);
  __syncthreads();                 // hB fully rewritten
}

template<bool XSTAGED>
__global__ __launch_bounds__(NTHREADS, 4)
void meganerf_fused(const float* __restrict__ x, const float* __restrict__ cent,
                    const float* __restrict__ b1, const float* __restrict__ b2,
                    const float* __restrict__ b3, const float* __restrict__ bo,
                    const unsigned short* __restrict__ wf,
                    const unsigned short* __restrict__ xs,
                    float* __restrict__ out) {
  __shared__ unsigned short hB[8 * KQH * 512];  // 65536 B: [mtile][kq][lane][8]
  __shared__ float wcl[MT * NE];                // 4096 B   -> total 69632 B

  const int tid = threadIdx.x;
  const int lane = tid & 63;
  const int wv = tid >> 6;      // 0..7
  const int wch = wv >> 1;      // channel group 0..3 (64 channels each)
  const int wpt = wv & 1;       // point group 0..1 (64 points each)
  const int l15 = lane & 15, l4 = lane >> 4;
  const int row0 = blockIdx.x * MT;

  // --- cluster weights (strict IEEE f32, no contraction: must bit-match np) ---
  if (tid < MT) {
    const int p = row0 + tid;
    float px = x[p*XC + 1], py = x[p*XC + 2];
    float d[NE]; float mind = 3.4e38f;
#pragma unroll
    for (int e = 0; e < NE; ++e) {
      float dx = px - cent[e*3 + 1];
      float dy = py - cent[e*3 + 2];
      d[e] = __fsqrt_rn(__fmul_rn(dx, dx) + __fmul_rn(dy, dy));
      mind = fminf(mind, d[e]);
    }
    float m = 1.5f * mind, s = 0.f, inv[NE];
#pragma unroll
    for (int e = 0; e < NE; ++e) {
      float iv = (d[e] > m) ? 0.f : 1.f / (d[e] + 1e-8f);
      inv[e] = iv; s += iv;
    }
#pragma unroll
    for (int e = 0; e < NE; ++e) wcl[tid*NE + e] = inv[e] / s;
  }
  __syncthreads();

  const unsigned short* fw1 = wf;
  const unsigned short* fw2 = wf + W1_ELEMS;
  const unsigned short* fw3 = fw2 + W2_ELEMS;
  const unsigned short* fwo = fw3 + W2_ELEMS;
  const unsigned short* xsb = xs + ((size_t)(blockIdx.x*8 + wpt*4)*KQ1)*512 + lane*8;

  float og[NOUT] = {0.f, 0.f, 0.f, 0.f};   // final gated outputs (l4==0 lanes own them)

  for (int e = 0; e < NE; ++e) {
    // ---- layer 1: h^T = relu(W1^T X^T + b1) -> hB ----
    {
      f32x4 acc[4][4];
#pragma unroll
      for (int cf = 0; cf < 4; ++cf) {
        f32x4 bv = *reinterpret_cast<const f32x4*>(&b1[e*HD + wch*64 + cf*16 + l4*4]);
#pragma unroll
        for (int pf = 0; pf < 4; ++pf)
          acc[cf][pf] = bv;
      }
#pragma unroll
      for (int kq = 0; kq < KQ1; ++kq) {
        bf16x8 aw[4];
#pragma unroll
        for (int cf = 0; cf < 4; ++cf)
          aw[cf] = *(const bf16x8*)(fw1 + (((e*NBH + wch*4 + cf)*KQ1 + kq) << 9) + lane*8);
#pragma unroll
        for (int pf = 0; pf < 4; ++pf) {
          bf16x8 bx;
          if constexpr (XSTAGED) {
            bx = *(const bf16x8*)(xsb + (pf*KQ1 + kq)*512);
          } else {
            const int row = row0 + wpt*64 + pf*16 + l15;
            const int kb = kq*32 + l4*8;
            const float* src = x + (size_t)row*XC + 3;
#pragma unroll
            for (int j = 0; j < 8; ++j)
              bx[j] = (short)((kb + j < FIN) ? f2bf(src[kb + j]) : (unsigned short)0);
          }
#pragma unroll
          for (int cf = 0; cf < 4; ++cf)
            acc[cf][pf] = __builtin_amdgcn_mfma_f32_16x16x32_bf16(aw[cf], bx, acc[cf][pf], 0, 0, 0);
        }
      }
      store_hB(acc, hB, wch, wpt, l15, l4);   // hB free: end-of-expert sync
    }
    __syncthreads();

    // ---- layer 2, layer 3: in-place hB ----
    layerH(hB, fw2 + (e << 16), b2 + e*HD, wch, wpt, l15, l4, lane);
    layerH(hB, fw3 + (e << 16), b3 + e*HD, wch, wpt, l15, l4, lane);

    // ---- layer 4: out^T = Wo^T h^T; wave wv owns point-tile wv ----
    {
      f32x4 acc = {0.f, 0.f, 0.f, 0.f};
#pragma unroll
      for (int kq = 0; kq < KQH; ++kq) {
        bf16x8 aw = *(const bf16x8*)(fwo + ((e*KQH + kq) << 9) + lane*8);
        bf16x8 bh = *(const bf16x8*)(hB + wv*4096 + kq*512 + lane*8);
        acc = __builtin_amdgcn_mfma_f32_16x16x32_bf16(aw, bh, acc, 0, 0, 0);
      }
      // D: col=l15 (point within tile wv), row=l4*4+j (output channel; 0..3 real)
      if (l4 == 0) {
        float w = wcl[(wv*16 + l15)*NE + e];
#pragma unroll
        for (int j = 0; j < NOUT; ++j)
          og[j] += w * (acc[j] + bo[e*NOUT + j]);
      }
    }
    __syncthreads();   // L4 reads of hB done; next expert's L1 may rewrite hB
  }

  if (l4 == 0) {
    f32x4 o = {og[0], og[1], og[2], og[3]};
    *reinterpret_cast<f32x4*>(&out[(size_t)(row0 + wv*16 + l15)*NOUT]) = o;
  }
}

extern "C" void kernel_launch(void* const* d_in, const int* in_sizes, int n_in,
                              void* d_out, int out_size, void* d_ws, size_t ws_size,
                              hipStream_t stream) {
  const float* x    = (const float*)d_in[0];
  const float* cent = (const float*)d_in[1];
  const float* W1   = (const float*)d_in[2];
  const float* b1   = (const float*)d_in[3];
  const float* W2   = (const float*)d_in[4];
  const float* b2   = (const float*)d_in[5];
  const float* W3   = (const float*)d_in[6];
  const float* b3   = (const float*)d_in[7];
  const float* Wo   = (const float*)d_in[8];
  const float* bo   = (const float*)d_in[9];
  float* out = (float*)d_out;
  unsigned short* wsb = (unsigned short*)d_ws;

  const int N = in_sizes[0] / XC;                 // 131072
  const int nfragX = (N/16) * KQ1;                // 24576 fragments
  const size_t wbytes = (size_t)WTOT * 2;         // 2,555,904
  const size_t xbytes = (size_t)nfragX * 512 * 2; // 25,165,824

  convert_weights<<<dim3((WTOT + 255) / 256), dim3(256), 0, stream>>>(W1, W2, W3, Wo, wsb);

  if (ws_size >= wbytes + xbytes) {
    unsigned short* xsb2 = wsb + WTOT;
    convert_x<<<dim3((nfragX*512 + 255) / 256), dim3(256), 0, stream>>>(x, xsb2, nfragX);
    meganerf_fused<true><<<dim3(N / MT), dim3(NTHREADS), 0, stream>>>(
        x, cent, b1, b2, b3, bo, wsb, xsb2, out);
  } else {
    meganerf_fused<false><<<dim3(N / MT), dim3(NTHREADS), 0, stream>>>(
        x, cent, b1, b2, b3, bo, wsb, wsb, out);
  }
}